// Round 7
// baseline (127.587 us; speedup 1.0000x reference)
//
#include <hip/hip_runtime.h>

#define B_SZ  4
#define N_TOK 4096   // H*W
#define CH    256
#define CR    32
#define SEG   512    // keys per wave (split-K segment), 8 waves/block
#define KT    128    // keys per iteration (2 x 64-key P/PV sub-phases)
#define NITER (SEG / KT)
#define LOG2E 1.44269504f
#define SHIFT2 (12.0f * 1.44269504f)   // softmax shift in exp2 domain

typedef __attribute__((ext_vector_type(8))) short bf16x8;  // 8 bf16 = 4 VGPRs
typedef __attribute__((ext_vector_type(4))) float f32x4;

__device__ inline ushort f2bf(float x) {           // RNE fp32->bf16
    uint u = __float_as_uint(x);
    u += 0x7fff + ((u >> 16) & 1);
    return (ushort)(u >> 16);
}
__device__ inline uint pk2bf(float a, float b) {   // [bf16(b)|bf16(a)], truncate
    return __builtin_amdgcn_perm(__float_as_uint(b), __float_as_uint(a), 0x07060302);
}

// ---------- Kernel 0: weight prep — Wf/Wg/Wh -> transposed bf16 [32][256]; Wv -> [256][32] bf16 ----------
__global__ __launch_bounds__(256) void prep_kernel(
    const float* __restrict__ Wf, const float* __restrict__ Wg,
    const float* __restrict__ Wh, const float* __restrict__ Wv,
    ushort* __restrict__ wft, ushort* __restrict__ wgt,
    ushort* __restrict__ wht, ushort* __restrict__ wvt)
{
    int t = threadIdx.x, blk = blockIdx.x;
    if (blk < 3) {
        const float* W  = (blk == 0) ? Wf : (blk == 1) ? Wg : Wh;
        ushort*      Wt = (blk == 0) ? wft : (blk == 1) ? wgt : wht;
        int j = t & 31, half = t >> 5;
        ushort tmp[32];
        #pragma unroll
        for (int kk = 0; kk < 32; ++kk)
            tmp[kk] = f2bf(W[(half * 32 + kk) * CR + j]);
        ushort* dst = Wt + (size_t)j * CH + half * 32;
        #pragma unroll
        for (int k8 = 0; k8 < 4; ++k8)
            *(bf16x8*)(dst + k8 * 8) = *(bf16x8*)&tmp[k8 * 8];
    } else {
        ushort tmp[32];
        #pragma unroll
        for (int k = 0; k < CR; ++k) tmp[k] = f2bf(Wv[k * CH + t]);
        ushort* dst = wvt + (size_t)t * CR;
        #pragma unroll
        for (int k8 = 0; k8 < 4; ++k8)
            *(bf16x8*)(dst + k8 * 8) = *(bf16x8*)&tmp[k8 * 8];
    }
}

// ---------- Kernel A: MFMA projections, 4-way split-K. g is scaled by log2(e). ----------
__global__ __launch_bounds__(256) void proj_kernel(
    const float* __restrict__ x,
    const ushort* __restrict__ wft, const ushort* __restrict__ wgt, const ushort* __restrict__ wht,
    const float* __restrict__ bf_, const float* __restrict__ bg, const float* __restrict__ bh,
    ushort* __restrict__ fo, ushort* __restrict__ go, ushort* __restrict__ hto)
{
    __shared__ f32x4 accx[3][6][64];   // partial accs from waves 1..3 (18 KB)
    int t  = threadIdx.x;
    int wv = t >> 6, L = t & 63, nl = L & 15, Q = L >> 4;
    int row_t = blockIdx.x * 16;
    int b = row_t >> 12, tok0 = row_t & 4095;

    const float* xrow = x + (size_t)(row_t + nl) * CH;
    f32x4 A[6];
    #pragma unroll
    for (int i = 0; i < 6; ++i) A[i] = (f32x4){0.f, 0.f, 0.f, 0.f};

    #pragma unroll
    for (int c2 = 0; c2 < 2; ++c2) {
        int off = wv * 64 + c2 * 32 + Q * 8;
        float4 lo = *(const float4*)(xrow + off);
        float4 hi = *(const float4*)(xrow + off + 4);
        bf16x8 xa;
        xa[0] = (short)f2bf(lo.x); xa[1] = (short)f2bf(lo.y);
        xa[2] = (short)f2bf(lo.z); xa[3] = (short)f2bf(lo.w);
        xa[4] = (short)f2bf(hi.x); xa[5] = (short)f2bf(hi.y);
        xa[6] = (short)f2bf(hi.z); xa[7] = (short)f2bf(hi.w);

        bf16x8 wf0 = *(const bf16x8*)(wft + (size_t)nl * CH + off);
        bf16x8 wf1 = *(const bf16x8*)(wft + (size_t)(16 + nl) * CH + off);
        bf16x8 wg0 = *(const bf16x8*)(wgt + (size_t)nl * CH + off);
        bf16x8 wg1 = *(const bf16x8*)(wgt + (size_t)(16 + nl) * CH + off);
        bf16x8 wh0 = *(const bf16x8*)(wht + (size_t)nl * CH + off);
        bf16x8 wh1 = *(const bf16x8*)(wht + (size_t)(16 + nl) * CH + off);

        A[0] = __builtin_amdgcn_mfma_f32_16x16x32_bf16(xa, wf0, A[0], 0, 0, 0);
        A[1] = __builtin_amdgcn_mfma_f32_16x16x32_bf16(xa, wf1, A[1], 0, 0, 0);
        A[2] = __builtin_amdgcn_mfma_f32_16x16x32_bf16(xa, wg0, A[2], 0, 0, 0);
        A[3] = __builtin_amdgcn_mfma_f32_16x16x32_bf16(xa, wg1, A[3], 0, 0, 0);
        A[4] = __builtin_amdgcn_mfma_f32_16x16x32_bf16(wh0, xa, A[4], 0, 0, 0);  // h^T
        A[5] = __builtin_amdgcn_mfma_f32_16x16x32_bf16(wh1, xa, A[5], 0, 0, 0);
    }

    if (wv > 0) {
        #pragma unroll
        for (int i = 0; i < 6; ++i) accx[wv - 1][i][L] = A[i];
    }
    __syncthreads();
    if (wv == 0) {
        #pragma unroll
        for (int i = 0; i < 6; ++i) {
            f32x4 s0 = accx[0][i][L], s1 = accx[1][i][L], s2 = accx[2][i][L];
            A[i] = A[i] + s0 + s1 + s2;
        }
        float bF0 = bf_[nl], bF1 = bf_[16 + nl];
        float bG0 = bg[nl] * LOG2E, bG1 = bg[16 + nl] * LOG2E;
        #pragma unroll
        for (int r = 0; r < 4; ++r) {
            size_t ro = (size_t)(row_t + Q * 4 + r) * CR;
            fo[ro + nl]      = f2bf(A[0][r] + bF0);
            fo[ro + 16 + nl] = f2bf(A[1][r] + bF1);
            go[ro + nl]      = f2bf(fmaf(A[2][r], LOG2E, bG0));
            go[ro + 16 + nl] = f2bf(fmaf(A[3][r], LOG2E, bG1));
        }
        ushort* hb = hto + (size_t)b * CR * N_TOK + tok0 + nl;
        #pragma unroll
        for (int r = 0; r < 4; ++r) {
            int ch = Q * 4 + r;
            hb[(size_t)ch * N_TOK]        = f2bf(A[4][r] + bh[ch]);
            hb[(size_t)(16 + ch) * N_TOK] = f2bf(A[5][r] + bh[16 + ch]);
        }
    }
}

// ---------- Kernel B: attention — 8 waves x 512-key split-K, 32 queries/block, KT=128 batched loads ----------
__global__ __launch_bounds__(512, 2) void attn_kernel(
    const ushort* __restrict__ f, const ushort* __restrict__ g,
    const ushort* __restrict__ ht, const ushort* __restrict__ wvt,
    const float* __restrict__ bv, const float* __restrict__ gamma,
    const float* __restrict__ x, float* __restrict__ out)
{
    // 38912 B shared, aliased: K-loop = pls[8][32][76] ushort;
    // post-barrier = obuf[8][32][33] f32 (33792) + lbuf[8][32] (1024) + oc[32][48] ushort (3072)
    __shared__ unsigned long long smem_raw[38912 / 8];
    ushort (*pls)[32][76]  = (ushort (*)[32][76])smem_raw;
    float  (*obuf)[32][33] = (float (*)[32][33])smem_raw;
    float  (*lbuf)[32]     = (float (*)[32])((char*)smem_raw + 33792);
    ushort (*oc)[48]       = (ushort (*)[48])((char*)smem_raw + 34816);

    int t  = threadIdx.x;
    int wv = t >> 6;
    int L  = t & 63;
    int nl = L & 15;
    int Q  = L >> 4;
    int b  = blockIdx.x >> 7;
    int q0 = (blockIdx.x & 127) * 32;

    const ushort* fb  = f  + (size_t)b * N_TOK * CR;
    const ushort* htb = ht + (size_t)b * CR * N_TOK;

    bf16x8 gB0 = *(const bf16x8*)(g + ((size_t)b * N_TOK + q0 + nl) * CR + Q * 8);
    bf16x8 gB1 = *(const bf16x8*)(g + ((size_t)b * N_TOK + q0 + 16 + nl) * CR + Q * 8);

    f32x4 acc00 = {0,0,0,0}, acc01 = {0,0,0,0};   // [qh][chhalf]
    f32x4 acc10 = {0,0,0,0}, acc11 = {0,0,0,0};
    const f32x4 zf = {0,0,0,0};
    float lsum0 = 0.f, lsum1 = 0.f;

    #pragma unroll 1
    for (int it = 0; it < NITER; ++it) {
        int kc = wv * SEG + it * KT;
        // --- batch-issue ALL 16 fragment loads for this iteration (independent) ---
        const ushort* fk = fb + (size_t)kc * CR;
        bf16x8 A[8];
        #pragma unroll
        for (int sk = 0; sk < 8; ++sk)
            A[sk] = *(const bf16x8*)(fk + (size_t)(sk * 16 + nl) * CR + Q * 8);
        const ushort* hk = htb + (size_t)nl * N_TOK + kc;
        bf16x8 Bv[8];   // [key32-chunk][ch-half]
        #pragma unroll
        for (int kq = 0; kq < 4; ++kq) {
            Bv[kq * 2 + 0] = *(const bf16x8*)(hk + kq * 32 + Q * 8);
            Bv[kq * 2 + 1] = *(const bf16x8*)(hk + (size_t)16 * N_TOK + kq * 32 + Q * 8);
        }

        // --- QK^T for both query halves: S^T[key][query], 128 keys ---
        f32x4 S0[8], S1[8];
        #pragma unroll
        for (int sk = 0; sk < 8; ++sk) {
            S0[sk] = __builtin_amdgcn_mfma_f32_16x16x32_bf16(A[sk], gB0, zf, 0, 0, 0);
            S1[sk] = __builtin_amdgcn_mfma_f32_16x16x32_bf16(A[sk], gB1, zf, 0, 0, 0);
        }

        // --- two 64-key sub-phases through the wave-private P tile ---
        #pragma unroll
        for (int sub = 0; sub < 2; ++sub) {
            #pragma unroll
            for (int qh = 0; qh < 2; ++qh) {
                int row = qh * 16 + nl;
                float s4 = 0.f;
                #pragma unroll
                for (int j = 0; j < 4; ++j) {
                    f32x4 sv = qh ? S1[sub * 4 + j] : S0[sub * 4 + j];
                    float p0 = exp2f(sv[0] - SHIFT2), p1 = exp2f(sv[1] - SHIFT2);
                    float p2 = exp2f(sv[2] - SHIFT2), p3 = exp2f(sv[3] - SHIFT2);
                    s4 += (p0 + p1) + (p2 + p3);
                    uint2 w; w.x = pk2bf(p0, p1); w.y = pk2bf(p2, p3);
                    *(uint2*)&pls[wv][row][j * 16 + Q * 4] = w;
                }
                if (qh) lsum1 += s4; else lsum0 += s4;
            }
            // read back as PV A-frags (DS in-order per wave: RAW/WAR safe)
            bf16x8 aP00 = *(const bf16x8*)&pls[wv][     nl][ 0 + Q * 8];
            bf16x8 aP01 = *(const bf16x8*)&pls[wv][     nl][32 + Q * 8];
            bf16x8 aP10 = *(const bf16x8*)&pls[wv][16 + nl][ 0 + Q * 8];
            bf16x8 aP11 = *(const bf16x8*)&pls[wv][16 + nl][32 + Q * 8];

            acc00 = __builtin_amdgcn_mfma_f32_16x16x32_bf16(aP00, Bv[sub * 4 + 0], acc00, 0, 0, 0);
            acc01 = __builtin_amdgcn_mfma_f32_16x16x32_bf16(aP00, Bv[sub * 4 + 1], acc01, 0, 0, 0);
            acc10 = __builtin_amdgcn_mfma_f32_16x16x32_bf16(aP10, Bv[sub * 4 + 0], acc10, 0, 0, 0);
            acc11 = __builtin_amdgcn_mfma_f32_16x16x32_bf16(aP10, Bv[sub * 4 + 1], acc11, 0, 0, 0);
            acc00 = __builtin_amdgcn_mfma_f32_16x16x32_bf16(aP01, Bv[sub * 4 + 2], acc00, 0, 0, 0);
            acc01 = __builtin_amdgcn_mfma_f32_16x16x32_bf16(aP01, Bv[sub * 4 + 3], acc01, 0, 0, 0);
            acc10 = __builtin_amdgcn_mfma_f32_16x16x32_bf16(aP11, Bv[sub * 4 + 2], acc10, 0, 0, 0);
            acc11 = __builtin_amdgcn_mfma_f32_16x16x32_bf16(aP11, Bv[sub * 4 + 3], acc11, 0, 0, 0);
        }
    }

    lsum0 += __shfl_xor(lsum0, 16); lsum0 += __shfl_xor(lsum0, 32);
    lsum1 += __shfl_xor(lsum1, 16); lsum1 += __shfl_xor(lsum1, 32);

    __syncthreads();   // all pls reads done before aliasing as obuf
    #pragma unroll
    for (int r = 0; r < 4; ++r) {
        obuf[wv][     Q * 4 + r][nl]      = acc00[r];
        obuf[wv][     Q * 4 + r][16 + nl] = acc01[r];
        obuf[wv][16 + Q * 4 + r][nl]      = acc10[r];
        obuf[wv][16 + Q * 4 + r][16 + nl] = acc11[r];
    }
    if (L < 16) { lbuf[wv][nl] = lsum0; lbuf[wv][16 + nl] = lsum1; }
    __syncthreads();

    {
        int ch = t & 31, qb = t >> 5;   // 512 thr -> 2 (q,ch) each
        #pragma unroll
        for (int qq = qb; qq < 32; qq += 16) {
            float s = 0.f, Lq = 0.f;
            #pragma unroll
            for (int w = 0; w < 8; ++w) { s += obuf[w][qq][ch]; Lq += lbuf[w][qq]; }
            oc[qq][ch] = f2bf(s / Lq);
        }
    }
    __syncthreads();

    // fused epilogue: out = gamma*(o@Wv + bv) + x ; wave wv covers out-ch [wv*32, wv*32+32)
    bf16x8 aO0 = *(const bf16x8*)&oc[     nl][Q * 8];
    bf16x8 aO1 = *(const bf16x8*)&oc[16 + nl][Q * 8];
    float gm = gamma[0];
    const float* xb = x   + ((size_t)b * N_TOK + q0) * CH;
    float*       ob = out + ((size_t)b * N_TOK + q0) * CH;
    #pragma unroll
    for (int i = 0; i < 2; ++i) {
        int nb = wv * 2 + i;
        bf16x8 bW = *(const bf16x8*)(wvt + (size_t)(nb * 16 + nl) * CR + Q * 8);
        f32x4 d0 = __builtin_amdgcn_mfma_f32_16x16x32_bf16(aO0, bW, zf, 0, 0, 0);
        f32x4 d1 = __builtin_amdgcn_mfma_f32_16x16x32_bf16(aO1, bW, zf, 0, 0, 0);
        int c = nb * 16 + nl;
        float bvc = bv[c];
        #pragma unroll
        for (int r = 0; r < 4; ++r) {
            int qa = Q * 4 + r;
            ob[qa * CH + c]        = fmaf(gm, d0[r] + bvc, xb[qa * CH + c]);
            ob[(16 + qa) * CH + c] = fmaf(gm, d1[r] + bvc, xb[(16 + qa) * CH + c]);
        }
    }
}

extern "C" void kernel_launch(void* const* d_in, const int* in_sizes, int n_in,
                              void* d_out, int out_size, void* d_ws, size_t ws_size,
                              hipStream_t stream) {
    const float* x     = (const float*)d_in[0];
    const float* Wf    = (const float*)d_in[1];
    const float* bf_   = (const float*)d_in[2];
    const float* Wg    = (const float*)d_in[3];
    const float* bg    = (const float*)d_in[4];
    const float* Wh    = (const float*)d_in[5];
    const float* bh    = (const float*)d_in[6];
    const float* Wv    = (const float*)d_in[7];
    const float* bv    = (const float*)d_in[8];
    const float* gamma = (const float*)d_in[9];
    float* out = (float*)d_out;

    const size_t T = (size_t)B_SZ * N_TOK * CR;     // 524288
    ushort* fo  = (ushort*)d_ws;
    ushort* go  = fo + T;
    ushort* hto = go + T;
    ushort* wvt = hto + T;                          // 256*32
    ushort* wft = wvt + CH * CR;                    // 32*256 each
    ushort* wgt = wft + CH * CR;
    ushort* wht = wgt + CH * CR;

    prep_kernel<<<4, 256, 0, stream>>>(Wf, Wg, Wh, Wv, wft, wgt, wht, wvt);
    proj_kernel<<<B_SZ * N_TOK / 16, 256, 0, stream>>>(x, wft, wgt, wht, bf_, bg, bh, fo, go, hto);
    attn_kernel<<<B_SZ * (N_TOK / 32), 512, 0, stream>>>(fo, go, hto, wvt, bv, gamma, x, out);
}

// Round 8
// 125.578 us; speedup vs baseline: 1.0160x; 1.0160x over previous
//
#include <hip/hip_runtime.h>

#define B_SZ  4
#define N_TOK 4096   // H*W
#define CH    256
#define CR    32
#define SEG   512    // keys per wave (split-K segment), 8 waves/block
#define KT    64     // keys per iteration
#define NITER (SEG / KT)
#define LOG2E 1.44269504f
#define SHIFT2 (12.0f * 1.44269504f)   // softmax shift in exp2 domain (g pre-scaled by log2e)

typedef __attribute__((ext_vector_type(8))) short bf16x8;  // 8 bf16 = 4 VGPRs
typedef __attribute__((ext_vector_type(4))) float f32x4;

__device__ inline ushort f2bf(float x) {           // RNE fp32->bf16
    uint u = __float_as_uint(x);
    u += 0x7fff + ((u >> 16) & 1);
    return (ushort)(u >> 16);
}
__device__ inline uint pk2bf(float a, float b) {   // [bf16(b)|bf16(a)], truncate
    return __builtin_amdgcn_perm(__float_as_uint(b), __float_as_uint(a), 0x07060302);
}

// ---------- Kernel 0: weight prep — Wf/Wg/Wh -> transposed bf16 [32][256]; Wv -> [256][32] bf16 ----------
__global__ __launch_bounds__(256) void prep_kernel(
    const float* __restrict__ Wf, const float* __restrict__ Wg,
    const float* __restrict__ Wh, const float* __restrict__ Wv,
    ushort* __restrict__ wft, ushort* __restrict__ wgt,
    ushort* __restrict__ wht, ushort* __restrict__ wvt)
{
    int t = threadIdx.x, blk = blockIdx.x;
    if (blk < 3) {
        const float* W  = (blk == 0) ? Wf : (blk == 1) ? Wg : Wh;
        ushort*      Wt = (blk == 0) ? wft : (blk == 1) ? wgt : wht;
        int j = t & 31, half = t >> 5;
        ushort tmp[32];
        #pragma unroll
        for (int kk = 0; kk < 32; ++kk)
            tmp[kk] = f2bf(W[(half * 32 + kk) * CR + j]);
        ushort* dst = Wt + (size_t)j * CH + half * 32;
        #pragma unroll
        for (int k8 = 0; k8 < 4; ++k8)
            *(bf16x8*)(dst + k8 * 8) = *(bf16x8*)&tmp[k8 * 8];
    } else {
        ushort tmp[32];
        #pragma unroll
        for (int k = 0; k < CR; ++k) tmp[k] = f2bf(Wv[k * CH + t]);
        ushort* dst = wvt + (size_t)t * CR;
        #pragma unroll
        for (int k8 = 0; k8 < 4; ++k8)
            *(bf16x8*)(dst + k8 * 8) = *(bf16x8*)&tmp[k8 * 8];
    }
}

// ---------- Kernel A: MFMA projections, 4-way split-K. g is scaled by log2(e). ----------
__global__ __launch_bounds__(256) void proj_kernel(
    const float* __restrict__ x,
    const ushort* __restrict__ wft, const ushort* __restrict__ wgt, const ushort* __restrict__ wht,
    const float* __restrict__ bf_, const float* __restrict__ bg, const float* __restrict__ bh,
    ushort* __restrict__ fo, ushort* __restrict__ go, ushort* __restrict__ hto)
{
    __shared__ f32x4 accx[3][6][64];   // partial accs from waves 1..3 (18 KB)
    int t  = threadIdx.x;
    int wv = t >> 6, L = t & 63, nl = L & 15, Q = L >> 4;
    int row_t = blockIdx.x * 16;
    int b = row_t >> 12, tok0 = row_t & 4095;

    const float* xrow = x + (size_t)(row_t + nl) * CH;
    f32x4 A[6];
    #pragma unroll
    for (int i = 0; i < 6; ++i) A[i] = (f32x4){0.f, 0.f, 0.f, 0.f};

    #pragma unroll
    for (int c2 = 0; c2 < 2; ++c2) {
        int off = wv * 64 + c2 * 32 + Q * 8;
        float4 lo = *(const float4*)(xrow + off);
        float4 hi = *(const float4*)(xrow + off + 4);
        bf16x8 xa;
        xa[0] = (short)f2bf(lo.x); xa[1] = (short)f2bf(lo.y);
        xa[2] = (short)f2bf(lo.z); xa[3] = (short)f2bf(lo.w);
        xa[4] = (short)f2bf(hi.x); xa[5] = (short)f2bf(hi.y);
        xa[6] = (short)f2bf(hi.z); xa[7] = (short)f2bf(hi.w);

        bf16x8 wf0 = *(const bf16x8*)(wft + (size_t)nl * CH + off);
        bf16x8 wf1 = *(const bf16x8*)(wft + (size_t)(16 + nl) * CH + off);
        bf16x8 wg0 = *(const bf16x8*)(wgt + (size_t)nl * CH + off);
        bf16x8 wg1 = *(const bf16x8*)(wgt + (size_t)(16 + nl) * CH + off);
        bf16x8 wh0 = *(const bf16x8*)(wht + (size_t)nl * CH + off);
        bf16x8 wh1 = *(const bf16x8*)(wht + (size_t)(16 + nl) * CH + off);

        A[0] = __builtin_amdgcn_mfma_f32_16x16x32_bf16(xa, wf0, A[0], 0, 0, 0);
        A[1] = __builtin_amdgcn_mfma_f32_16x16x32_bf16(xa, wf1, A[1], 0, 0, 0);
        A[2] = __builtin_amdgcn_mfma_f32_16x16x32_bf16(xa, wg0, A[2], 0, 0, 0);
        A[3] = __builtin_amdgcn_mfma_f32_16x16x32_bf16(xa, wg1, A[3], 0, 0, 0);
        A[4] = __builtin_amdgcn_mfma_f32_16x16x32_bf16(wh0, xa, A[4], 0, 0, 0);  // h^T
        A[5] = __builtin_amdgcn_mfma_f32_16x16x32_bf16(wh1, xa, A[5], 0, 0, 0);
    }

    if (wv > 0) {
        #pragma unroll
        for (int i = 0; i < 6; ++i) accx[wv - 1][i][L] = A[i];
    }
    __syncthreads();
    if (wv == 0) {
        #pragma unroll
        for (int i = 0; i < 6; ++i) {
            f32x4 s0 = accx[0][i][L], s1 = accx[1][i][L], s2 = accx[2][i][L];
            A[i] = A[i] + s0 + s1 + s2;
        }
        float bF0 = bf_[nl], bF1 = bf_[16 + nl];
        float bG0 = bg[nl] * LOG2E, bG1 = bg[16 + nl] * LOG2E;
        #pragma unroll
        for (int r = 0; r < 4; ++r) {
            size_t ro = (size_t)(row_t + Q * 4 + r) * CR;
            fo[ro + nl]      = f2bf(A[0][r] + bF0);
            fo[ro + 16 + nl] = f2bf(A[1][r] + bF1);
            go[ro + nl]      = f2bf(fmaf(A[2][r], LOG2E, bG0));
            go[ro + 16 + nl] = f2bf(fmaf(A[3][r], LOG2E, bG1));
        }
        ushort* hb = hto + (size_t)b * CR * N_TOK + tok0 + nl;
        #pragma unroll
        for (int r = 0; r < 4; ++r) {
            int ch = Q * 4 + r;
            hb[(size_t)ch * N_TOK]        = f2bf(A[4][r] + bh[ch]);
            hb[(size_t)(16 + ch) * N_TOK] = f2bf(A[5][r] + bh[16 + ch]);
        }
    }
}

// ---------- Kernel B: attention — 8 waves x 512-key split-K, 32 q/block, full A+B double-prefetch ----------
__global__ __launch_bounds__(512, 4) void attn_kernel(
    const ushort* __restrict__ f, const ushort* __restrict__ g,
    const ushort* __restrict__ ht, const ushort* __restrict__ wvt,
    const float* __restrict__ bv, const float* __restrict__ gamma,
    const float* __restrict__ x, float* __restrict__ out)
{
    // 38912 B shared, aliased: K-loop = pls[8][32][76] ushort;
    // post-barrier = obuf[8][32][33] f32 (33792) + lbuf[8][32] (1024) + oc[32][48] ushort (3072)
    __shared__ unsigned long long smem_raw[38912 / 8];
    ushort (*pls)[32][76]  = (ushort (*)[32][76])smem_raw;
    float  (*obuf)[32][33] = (float (*)[32][33])smem_raw;
    float  (*lbuf)[32]     = (float (*)[32])((char*)smem_raw + 33792);
    ushort (*oc)[48]       = (ushort (*)[48])((char*)smem_raw + 34816);

    int t  = threadIdx.x;
    int wv = t >> 6;
    int L  = t & 63;
    int nl = L & 15;
    int Q  = L >> 4;
    int b  = blockIdx.x >> 7;
    int q0 = (blockIdx.x & 127) * 32;

    const ushort* fb  = f  + (size_t)b * N_TOK * CR;
    const ushort* htb = ht + (size_t)b * CR * N_TOK;

    bf16x8 gB0 = *(const bf16x8*)(g + ((size_t)b * N_TOK + q0 + nl) * CR + Q * 8);
    bf16x8 gB1 = *(const bf16x8*)(g + ((size_t)b * N_TOK + q0 + 16 + nl) * CR + Q * 8);

    f32x4 acc00 = {0,0,0,0}, acc01 = {0,0,0,0};   // [qh][chhalf]
    f32x4 acc10 = {0,0,0,0}, acc11 = {0,0,0,0};
    const f32x4 zf = {0,0,0,0};
    float lsum0 = 0.f, lsum1 = 0.f;

    // prologue: load iter-0 A (QK f-frags) and B (PV ht-frags)
    int k0 = wv * SEG;
    bf16x8 Ac0 = *(const bf16x8*)(fb + (size_t)(k0 +  0 + nl) * CR + Q * 8);
    bf16x8 Ac1 = *(const bf16x8*)(fb + (size_t)(k0 + 16 + nl) * CR + Q * 8);
    bf16x8 Ac2 = *(const bf16x8*)(fb + (size_t)(k0 + 32 + nl) * CR + Q * 8);
    bf16x8 Ac3 = *(const bf16x8*)(fb + (size_t)(k0 + 48 + nl) * CR + Q * 8);
    const ushort* h0 = htb + (size_t)nl * N_TOK + k0;
    bf16x8 Bc0 = *(const bf16x8*)(h0 + Q * 8);
    bf16x8 Bc1 = *(const bf16x8*)(h0 + (size_t)16 * N_TOK + Q * 8);
    bf16x8 Bc2 = *(const bf16x8*)(h0 + 32 + Q * 8);
    bf16x8 Bc3 = *(const bf16x8*)(h0 + (size_t)16 * N_TOK + 32 + Q * 8);

    #pragma unroll 2
    for (int it = 0; it < NITER; ++it) {
        // issue iter i+1's 8 fragment loads up-front (full-iteration latency budget)
        int kn = wv * SEG + ((it + 1) & (NITER - 1)) * KT;
        const ushort* fn = fb + (size_t)kn * CR;
        bf16x8 An0 = *(const bf16x8*)(fn + (size_t)( 0 + nl) * CR + Q * 8);
        bf16x8 An1 = *(const bf16x8*)(fn + (size_t)(16 + nl) * CR + Q * 8);
        bf16x8 An2 = *(const bf16x8*)(fn + (size_t)(32 + nl) * CR + Q * 8);
        bf16x8 An3 = *(const bf16x8*)(fn + (size_t)(48 + nl) * CR + Q * 8);
        const ushort* hn = htb + (size_t)nl * N_TOK + kn;
        bf16x8 Bn0 = *(const bf16x8*)(hn + Q * 8);
        bf16x8 Bn1 = *(const bf16x8*)(hn + (size_t)16 * N_TOK + Q * 8);
        bf16x8 Bn2 = *(const bf16x8*)(hn + 32 + Q * 8);
        bf16x8 Bn3 = *(const bf16x8*)(hn + (size_t)16 * N_TOK + 32 + Q * 8);

        // QK^T tile-by-tile; consume S immediately (keeps S live-range = 8 regs)
        #pragma unroll
        for (int sk = 0; sk < 4; ++sk) {
            bf16x8 Ak = (sk == 0) ? Ac0 : (sk == 1) ? Ac1 : (sk == 2) ? Ac2 : Ac3;
            f32x4 s0 = __builtin_amdgcn_mfma_f32_16x16x32_bf16(Ak, gB0, zf, 0, 0, 0);
            f32x4 s1 = __builtin_amdgcn_mfma_f32_16x16x32_bf16(Ak, gB1, zf, 0, 0, 0);
            float p0 = exp2f(s0[0] - SHIFT2), p1 = exp2f(s0[1] - SHIFT2);
            float p2 = exp2f(s0[2] - SHIFT2), p3 = exp2f(s0[3] - SHIFT2);
            lsum0 += (p0 + p1) + (p2 + p3);
            uint2 w; w.x = pk2bf(p0, p1); w.y = pk2bf(p2, p3);
            *(uint2*)&pls[wv][nl][sk * 16 + Q * 4] = w;
            p0 = exp2f(s1[0] - SHIFT2); p1 = exp2f(s1[1] - SHIFT2);
            p2 = exp2f(s1[2] - SHIFT2); p3 = exp2f(s1[3] - SHIFT2);
            lsum1 += (p0 + p1) + (p2 + p3);
            w.x = pk2bf(p0, p1); w.y = pk2bf(p2, p3);
            *(uint2*)&pls[wv][16 + nl][sk * 16 + Q * 4] = w;
        }

        // read back as PV A-frags (DS in-order per wave: RAW safe, compiler emits lgkmcnt)
        bf16x8 aP00 = *(const bf16x8*)&pls[wv][     nl][ 0 + Q * 8];
        bf16x8 aP01 = *(const bf16x8*)&pls[wv][     nl][32 + Q * 8];
        bf16x8 aP10 = *(const bf16x8*)&pls[wv][16 + nl][ 0 + Q * 8];
        bf16x8 aP11 = *(const bf16x8*)&pls[wv][16 + nl][32 + Q * 8];

        acc00 = __builtin_amdgcn_mfma_f32_16x16x32_bf16(aP00, Bc0, acc00, 0, 0, 0);
        acc01 = __builtin_amdgcn_mfma_f32_16x16x32_bf16(aP00, Bc1, acc01, 0, 0, 0);
        acc10 = __builtin_amdgcn_mfma_f32_16x16x32_bf16(aP10, Bc0, acc10, 0, 0, 0);
        acc11 = __builtin_amdgcn_mfma_f32_16x16x32_bf16(aP10, Bc1, acc11, 0, 0, 0);
        acc00 = __builtin_amdgcn_mfma_f32_16x16x32_bf16(aP01, Bc2, acc00, 0, 0, 0);
        acc01 = __builtin_amdgcn_mfma_f32_16x16x32_bf16(aP01, Bc3, acc01, 0, 0, 0);
        acc10 = __builtin_amdgcn_mfma_f32_16x16x32_bf16(aP11, Bc2, acc10, 0, 0, 0);
        acc11 = __builtin_amdgcn_mfma_f32_16x16x32_bf16(aP11, Bc3, acc11, 0, 0, 0);

        Ac0 = An0; Ac1 = An1; Ac2 = An2; Ac3 = An3;
        Bc0 = Bn0; Bc1 = Bn1; Bc2 = Bn2; Bc3 = Bn3;
    }

    lsum0 += __shfl_xor(lsum0, 16); lsum0 += __shfl_xor(lsum0, 32);
    lsum1 += __shfl_xor(lsum1, 16); lsum1 += __shfl_xor(lsum1, 32);

    __syncthreads();   // all pls reads done before aliasing as obuf
    #pragma unroll
    for (int r = 0; r < 4; ++r) {
        obuf[wv][     Q * 4 + r][nl]      = acc00[r];
        obuf[wv][     Q * 4 + r][16 + nl] = acc01[r];
        obuf[wv][16 + Q * 4 + r][nl]      = acc10[r];
        obuf[wv][16 + Q * 4 + r][16 + nl] = acc11[r];
    }
    if (L < 16) { lbuf[wv][nl] = lsum0; lbuf[wv][16 + nl] = lsum1; }
    __syncthreads();

    {
        int ch = t & 31, qb = t >> 5;   // 512 thr -> 2 (q,ch) each
        #pragma unroll
        for (int qq = qb; qq < 32; qq += 16) {
            float s = 0.f, Lq = 0.f;
            #pragma unroll
            for (int w = 0; w < 8; ++w) { s += obuf[w][qq][ch]; Lq += lbuf[w][qq]; }
            oc[qq][ch] = f2bf(s / Lq);
        }
    }
    __syncthreads();

    // fused epilogue: out = gamma*(o@Wv + bv) + x ; wave wv covers out-ch [wv*32, wv*32+32)
    bf16x8 aO0 = *(const bf16x8*)&oc[     nl][Q * 8];
    bf16x8 aO1 = *(const bf16x8*)&oc[16 + nl][Q * 8];
    float gm = gamma[0];
    const float* xb = x   + ((size_t)b * N_TOK + q0) * CH;
    float*       ob = out + ((size_t)b * N_TOK + q0) * CH;
    #pragma unroll
    for (int i = 0; i < 2; ++i) {
        int nb = wv * 2 + i;
        bf16x8 bW = *(const bf16x8*)(wvt + (size_t)(nb * 16 + nl) * CR + Q * 8);
        f32x4 d0 = __builtin_amdgcn_mfma_f32_16x16x32_bf16(aO0, bW, zf, 0, 0, 0);
        f32x4 d1 = __builtin_amdgcn_mfma_f32_16x16x32_bf16(aO1, bW, zf, 0, 0, 0);
        int c = nb * 16 + nl;
        float bvc = bv[c];
        #pragma unroll
        for (int r = 0; r < 4; ++r) {
            int qa = Q * 4 + r;
            ob[qa * CH + c]        = fmaf(gm, d0[r] + bvc, xb[qa * CH + c]);
            ob[(16 + qa) * CH + c] = fmaf(gm, d1[r] + bvc, xb[(16 + qa) * CH + c]);
        }
    }
}

extern "C" void kernel_launch(void* const* d_in, const int* in_sizes, int n_in,
                              void* d_out, int out_size, void* d_ws, size_t ws_size,
                              hipStream_t stream) {
    const float* x     = (const float*)d_in[0];
    const float* Wf    = (const float*)d_in[1];
    const float* bf_   = (const float*)d_in[2];
    const float* Wg    = (const float*)d_in[3];
    const float* bg    = (const float*)d_in[4];
    const float* Wh    = (const float*)d_in[5];
    const float* bh    = (const float*)d_in[6];
    const float* Wv    = (const float*)d_in[7];
    const float* bv    = (const float*)d_in[8];
    const float* gamma = (const float*)d_in[9];
    float* out = (float*)d_out;

    const size_t T = (size_t)B_SZ * N_TOK * CR;     // 524288
    ushort* fo  = (ushort*)d_ws;
    ushort* go  = fo + T;
    ushort* hto = go + T;
    ushort* wvt = hto + T;                          // 256*32
    ushort* wft = wvt + CH * CR;                    // 32*256 each
    ushort* wgt = wft + CH * CR;
    ushort* wht = wgt + CH * CR;

    prep_kernel<<<4, 256, 0, stream>>>(Wf, Wg, Wh, Wv, wft, wgt, wht, wvt);
    proj_kernel<<<B_SZ * N_TOK / 16, 256, 0, stream>>>(x, wft, wgt, wht, bf_, bg, bh, fo, go, hto);
    attn_kernel<<<B_SZ * (N_TOK / 32), 512, 0, stream>>>(fo, go, hto, wvt, bv, gamma, x, out);
}